// Round 1
// baseline (77082.953 us; speedup 1.0000x reference)
//
#include <hip/hip_runtime.h>
#include <stdint.h>

// ---------------- ws layout (bytes) ----------------
// hT0: double-buffered h0, layout [buf][k/4][b][4] f32 : 2*1024*256*4 = 2 MB
// hT1: same for h1                                      : 2 MB
// seq: [84][256] f32                                    : 86016
// part: [256 blk][256 b] f32 (fc partials)              : 262144
// bar: 2 u32 grid-barrier state
#define HT0_OFFF   0u          // float offsets
#define HT1_OFFF   524288u
#define SEQ_OFFF   1048576u
#define PART_OFFF  1070080u
#define BAR_OFFB   4542464u    // byte offset
#define WS_NEEDED  4542528u

#define JAX_PARTITIONABLE 1

__device__ __forceinline__ unsigned rotl32(unsigned x, int d){ return (x<<d)|(x>>(32-d)); }

// Threefry-2x32, 20 rounds, exactly JAX's key schedule.
__device__ __forceinline__ uint2 tf2x32(unsigned k0, unsigned k1, unsigned x0, unsigned x1){
  unsigned kx = k0 ^ k1 ^ 0x1BD11BDAu;
  x0 += k0; x1 += k1;
#define TFR(r) { x0 += x1; x1 = rotl32(x1,(r)); x1 ^= x0; }
  TFR(13) TFR(15) TFR(26) TFR(6)  x0 += k1; x1 += kx + 1u;
  TFR(17) TFR(29) TFR(16) TFR(24) x0 += kx; x1 += k0 + 2u;
  TFR(13) TFR(15) TFR(26) TFR(6)  x0 += k0; x1 += k1 + 3u;
  TFR(17) TFR(29) TFR(16) TFR(24) x0 += k1; x1 += kx + 4u;
  TFR(13) TFR(15) TFR(26) TFR(6)  x0 += kx; x1 += k0 + 5u;
#undef TFR
  return make_uint2(x0, x1);
}

// keep-bit of JAX dropout: bernoulli(fold_in(key(42), t), 0.8) at flat index n = b*1024+j
__device__ __forceinline__ bool drop_keep(uint2 fk, unsigned n){
#if JAX_PARTITIONABLE
  uint2 o = tf2x32(fk.x, fk.y, 0u, n);
  unsigned bits = o.x ^ o.y;
#else
  unsigned bits;
  if (n < 131072u){ uint2 o = tf2x32(fk.x, fk.y, n, n + 131072u); bits = o.x; }
  else            { uint2 o = tf2x32(fk.x, fk.y, n - 131072u, n); bits = o.y; }
#endif
  float u = __uint_as_float((bits >> 9) | 0x3f800000u) - 1.0f;
  return u < 0.8f;
}

__device__ __forceinline__ float sigf(float x){ return 1.0f/(1.0f + __expf(-x)); }
__device__ __forceinline__ float thf(float x){ return 1.0f - 2.0f/(__expf(2.0f*x) + 1.0f); }

// device-scope grid barrier; epoch-monotonic (no counter reset races).
__device__ __forceinline__ void gbar(unsigned* cnt, unsigned* gate, unsigned e){
  __syncthreads();
  if (threadIdx.x == 0){
    __threadfence();
    unsigned prev = __hip_atomic_fetch_add(cnt, 1u, __ATOMIC_ACQ_REL, __HIP_MEMORY_SCOPE_AGENT);
    if (prev == e*256u - 1u){
      __hip_atomic_store(gate, e, __ATOMIC_RELEASE, __HIP_MEMORY_SCOPE_AGENT);
    } else {
      while (__hip_atomic_load(gate, __ATOMIC_ACQUIRE, __HIP_MEMORY_SCOPE_AGENT) < e)
        __builtin_amdgcn_s_sleep(2);
    }
    __threadfence();
  }
  __syncthreads();
}

// ---- prep: zero h buffers (buffer 0) + barrier state; runs every call ----
__global__ void k_init(float* __restrict__ ws_f, unsigned* __restrict__ bar){
  unsigned i = blockIdx.x*blockDim.x + threadIdx.x;
  if (i < 262144u){
    ws_f[HT0_OFFF + i] = 0.f;
    ws_f[HT1_OFFF + i] = 0.f;
  }
  if (i == 0u){ bar[0] = 0u; bar[1] = 0u; }
}

// ---- prep: conv1d(pad1,k3) + relu + maxpool2 -> seq[84][256] ----
__global__ void k_seq(const float* __restrict__ x, const float* __restrict__ cw,
                      const float* __restrict__ cb, float* __restrict__ seq){
  const int q = blockIdx.x;      // 0..83
  const int b = threadIdx.x;     // 0..255
  float best = -1e30f;
#pragma unroll
  for (int ssub = 0; ssub < 2; ++ssub){
    int p = 2*q + ssub;
    float acc = cb[0];
#pragma unroll
    for (int k = 0; k < 3; ++k){
      int t = p - 1 + k;
      if (t >= 0 && t < 168){
        const float* xp = x + ((size_t)b*192 + t)*8;
#pragma unroll
        for (int i = 0; i < 8; ++i) acc = fmaf(xp[i], cw[i*3 + k], acc);
      }
    }
    acc  = fmaxf(acc, 0.0f);
    best = fmaxf(best, acc);
  }
  seq[(q<<8) + b] = best;
}

// ---- main persistent kernel: 107 LSTM steps + fc/dropout head ----
__global__ void __launch_bounds__(256) k_main(
    const float* __restrict__ Wih0, const float* __restrict__ Whh0,
    const float* __restrict__ bih0, const float* __restrict__ bhh0,
    const float* __restrict__ Wih1, const float* __restrict__ Whh1,
    const float* __restrict__ bih1, const float* __restrict__ bhh1,
    const float* __restrict__ fc_w, const float* __restrict__ fc_b,
    float* __restrict__ ws_f, unsigned* __restrict__ bar, float* __restrict__ out)
{
  const int blk = blockIdx.x;    // 0..255, owns hidden units 4*blk..4*blk+3
  const int b   = threadIdx.x;   // batch
  const int j0  = blk << 2;

  float* hT0 = ws_f + HT0_OFFF;
  float* hT1 = ws_f + HT1_OFFF;
  const float* seq = ws_f + SEQ_OFFF;
  float* part = ws_f + PART_OFFF;
  unsigned* bcnt = bar; unsigned* bgate = bar + 1;

  // per-block row constants (uniform -> sgpr)
  float bias0[16], bias1[16], wi0[16];
#pragma unroll
  for (int i = 0; i < 16; ++i){
    int u = i >> 2, g = i & 3;
    int row = (g << 10) + j0 + u;          // PyTorch gate order i,f,g,o
    bias0[i] = bih0[row] + bhh0[row];
    bias1[i] = bih1[row] + bhh1[row];
    wi0[i]   = Wih0[row];                  // Wih0 is [4096,1]
  }
  float fcw[4];
#pragma unroll
  for (int u = 0; u < 4; ++u) fcw[u] = fc_w[j0 + u] * 1.25f;   // fold /KEEP
  const float fcb = fc_b[0];

  float c0[4] = {0,0,0,0}, c1[4] = {0,0,0,0};

#pragma unroll 1
  for (int s = 0; s < 107; ++s){
    const int src = s & 1, dst = src ^ 1;
    const float* h0s = hT0 + src*262144;
    float*       h0d = hT0 + dst*262144;
    const float* h1s = hT1 + src*262144;
    float*       h1d = hT1 + dst*262144;

    // ---- input x_t ----
    float xb;
    if (s < 84){
      xb = seq[(s << 8) + b];
    } else {
      float acc = fcb;                      // reduce fc partials -> y_{s-84}
#pragma unroll 4
      for (int p = 0; p < 256; ++p) acc += part[(p << 8) + b];
      xb = acc;
      if (blk == 0) out[b*24 + (s - 84)] = acc;
    }

    // ---- phase A: layer-0 gates g = h0 @ Whh0^T + x*wih0 + b0 ----
    float acc[16];
#pragma unroll
    for (int i = 0; i < 16; ++i) acc[i] = fmaf(xb, wi0[i], bias0[i]);
    for (int kq = 0; kq < 256; ++kq){
      const float4 hv = *reinterpret_cast<const float4*>(h0s + (kq << 10) + (b << 2));
      const int k = kq << 2;
#pragma unroll
      for (int i = 0; i < 16; ++i){
        int u = i >> 2, g = i & 3;
        const float* wp = Whh0 + (((size_t)((g << 10) + j0 + u)) << 10) + k;
        acc[i] = fmaf(hv.x, wp[0], acc[i]);
        acc[i] = fmaf(hv.y, wp[1], acc[i]);
        acc[i] = fmaf(hv.z, wp[2], acc[i]);
        acc[i] = fmaf(hv.w, wp[3], acc[i]);
      }
    }
    float hn0[4];
#pragma unroll
    for (int u = 0; u < 4; ++u){
      float ig = sigf(acc[u*4+0]);
      float fg = sigf(acc[u*4+1]);
      float gg = thf (acc[u*4+2]);
      float og = sigf(acc[u*4+3]);
      c0[u] = fg*c0[u] + ig*gg;
      hn0[u] = og * thf(c0[u]);
    }
    *reinterpret_cast<float4*>(h0d + (blk << 10) + (b << 2)) =
        make_float4(hn0[0], hn0[1], hn0[2], hn0[3]);

    gbar(bcnt, bgate, 2u*(unsigned)s + 1u);

    // ---- phase B: layer-1 gates g = h0_new @ Wih1^T + h1 @ Whh1^T + b1 ----
#pragma unroll
    for (int i = 0; i < 16; ++i) acc[i] = bias1[i];
#pragma unroll 1
    for (int kq = 0; kq < 256; ++kq){
      const float4 ha = *reinterpret_cast<const float4*>(h0d + (kq << 10) + (b << 2));
      const float4 hb = *reinterpret_cast<const float4*>(h1s + (kq << 10) + (b << 2));
      const int k = kq << 2;
#pragma unroll
      for (int i = 0; i < 16; ++i){
        int u = i >> 2, g = i & 3;
        size_t ro = ((size_t)((g << 10) + j0 + u)) << 10;
        const float* wpa = Wih1 + ro + k;
        const float* wpb = Whh1 + ro + k;
        acc[i] = fmaf(ha.x, wpa[0], acc[i]);
        acc[i] = fmaf(ha.y, wpa[1], acc[i]);
        acc[i] = fmaf(ha.z, wpa[2], acc[i]);
        acc[i] = fmaf(ha.w, wpa[3], acc[i]);
        acc[i] = fmaf(hb.x, wpb[0], acc[i]);
        acc[i] = fmaf(hb.y, wpb[1], acc[i]);
        acc[i] = fmaf(hb.z, wpb[2], acc[i]);
        acc[i] = fmaf(hb.w, wpb[3], acc[i]);
      }
    }
    float hn1[4];
#pragma unroll
    for (int u = 0; u < 4; ++u){
      float ig = sigf(acc[u*4+0]);
      float fg = sigf(acc[u*4+1]);
      float gg = thf (acc[u*4+2]);
      float og = sigf(acc[u*4+3]);
      c1[u] = fg*c1[u] + ig*gg;
      hn1[u] = og * thf(c1[u]);
    }
    *reinterpret_cast<float4*>(h1d + (blk << 10) + (b << 2)) =
        make_float4(hn1[0], hn1[1], hn1[2], hn1[3]);

    // ---- fc partials with exact JAX dropout (mask tau = s-83) ----
    if (s >= 83){
      const unsigned tau = (unsigned)(s - 83);
      uint2 fk = tf2x32(0u, 42u, 0u, tau);      // fold_in(key(42), tau)
      float pb = 0.f;
#pragma unroll
      for (int u = 0; u < 4; ++u){
        unsigned n = ((unsigned)b << 10) + (unsigned)(j0 + u);
        if (drop_keep(fk, n)) pb += hn1[u] * fcw[u];
      }
      part[(blk << 8) + b] = pb;
    }

    gbar(bcnt, bgate, 2u*(unsigned)s + 2u);
  }

  // tail: y_23 from partials of step s=106 (mask 23)
  if (blk == 0){
    float acc = fcb;
#pragma unroll 4
    for (int p = 0; p < 256; ++p) acc += part[(p << 8) + b];
    out[b*24 + 23] = acc;
  }
}

extern "C" void kernel_launch(void* const* d_in, const int* in_sizes, int n_in,
                              void* d_out, int out_size, void* d_ws, size_t ws_size,
                              hipStream_t stream)
{
  const float* x    = (const float*)d_in[0];
  const float* cw   = (const float*)d_in[1];
  const float* cb   = (const float*)d_in[2];
  const float* Wih0 = (const float*)d_in[3];
  const float* Whh0 = (const float*)d_in[4];
  const float* bih0 = (const float*)d_in[5];
  const float* bhh0 = (const float*)d_in[6];
  const float* Wih1 = (const float*)d_in[7];
  const float* Whh1 = (const float*)d_in[8];
  const float* bih1 = (const float*)d_in[9];
  const float* bhh1 = (const float*)d_in[10];
  const float* fc_w = (const float*)d_in[11];
  const float* fc_b = (const float*)d_in[12];
  float* out  = (float*)d_out;
  float* ws_f = (float*)d_ws;
  unsigned* bar = (unsigned*)((uint8_t*)d_ws + BAR_OFFB);

  hipLaunchKernelGGL(k_init, dim3(1024), dim3(256), 0, stream, ws_f, bar);
  hipLaunchKernelGGL(k_seq,  dim3(84),   dim3(256), 0, stream, x, cw, cb, ws_f + SEQ_OFFF);
  hipLaunchKernelGGL(k_main, dim3(256),  dim3(256), 0, stream,
                     Wih0, Whh0, bih0, bhh0, Wih1, Whh1, bih1, bhh1,
                     fc_w, fc_b, ws_f, bar, out);
}

// Round 2
// 17470.703 us; speedup vs baseline: 4.4121x; 4.4121x over previous
//
#include <hip/hip_runtime.h>
#include <stdint.h>

typedef _Float16 f16;
typedef f16  f16x8 __attribute__((ext_vector_type(8)));
typedef float f32x4 __attribute__((ext_vector_type(4)));

// ---------------- ws layout (byte offsets) ----------------
// H0: h0 state, 2 bufs x (hi,lo) x [k/8][b][8] f16 = 2 MB
// H1: same for h1                                  = 2 MB
// SEQ: [84][256] f32 encoder inputs
// YACC: [24][256] f32 fc accumulators (atomicAdd targets)
// BAR: grid-barrier state
#define H0_OFF   0u
#define H1_OFF   2097152u
#define SEQ_OFF  4194304u
#define YACC_OFF 4280320u
#define BAR_OFF  4304896u

__device__ __forceinline__ unsigned rotl32(unsigned x, int d){ return (x<<d)|(x>>(32-d)); }

// Threefry-2x32, 20 rounds, exactly JAX's key schedule. (verified bit-exact in R1)
__device__ __forceinline__ uint2 tf2x32(unsigned k0, unsigned k1, unsigned x0, unsigned x1){
  unsigned kx = k0 ^ k1 ^ 0x1BD11BDAu;
  x0 += k0; x1 += k1;
#define TFR(r) { x0 += x1; x1 = rotl32(x1,(r)); x1 ^= x0; }
  TFR(13) TFR(15) TFR(26) TFR(6)  x0 += k1; x1 += kx + 1u;
  TFR(17) TFR(29) TFR(16) TFR(24) x0 += kx; x1 += k0 + 2u;
  TFR(13) TFR(15) TFR(26) TFR(6)  x0 += k0; x1 += k1 + 3u;
  TFR(17) TFR(29) TFR(16) TFR(24) x0 += k1; x1 += kx + 4u;
  TFR(13) TFR(15) TFR(26) TFR(6)  x0 += kx; x1 += k0 + 5u;
#undef TFR
  return make_uint2(x0, x1);
}

__device__ __forceinline__ bool drop_keep(uint2 fk, unsigned n){
  uint2 o = tf2x32(fk.x, fk.y, 0u, n);
  unsigned bits = o.x ^ o.y;
  float u = __uint_as_float((bits >> 9) | 0x3f800000u) - 1.0f;
  return u < 0.8f;
}

__device__ __forceinline__ float sigf(float x){ return 1.0f/(1.0f + __expf(-x)); }
__device__ __forceinline__ float thf(float x){ return 1.0f - 2.0f/(__expf(2.0f*x) + 1.0f); }

// device-scope grid barrier; epoch-monotonic (proven in R1).
__device__ __forceinline__ void gbar(unsigned* cnt, unsigned* gate, unsigned e){
  __syncthreads();
  if (threadIdx.x == 0){
    __threadfence();
    unsigned prev = __hip_atomic_fetch_add(cnt, 1u, __ATOMIC_ACQ_REL, __HIP_MEMORY_SCOPE_AGENT);
    if (prev == e*256u - 1u){
      __hip_atomic_store(gate, e, __ATOMIC_RELEASE, __HIP_MEMORY_SCOPE_AGENT);
    } else {
      while (__hip_atomic_load(gate, __ATOMIC_ACQUIRE, __HIP_MEMORY_SCOPE_AGENT) < e)
        __builtin_amdgcn_s_sleep(2);
    }
    __threadfence();
  }
  __syncthreads();
}

// ---- prep: zero h buffers + y_acc + barrier state ----
__global__ void k_init(uint4* __restrict__ hz, uint4* __restrict__ yz, unsigned* __restrict__ bar){
  unsigned i = blockIdx.x*256u + threadIdx.x;
  if (i < 262144u){ hz[i] = uint4{0,0,0,0}; }
  else { unsigned r = i - 262144u; if (r < 1536u) yz[r] = uint4{0,0,0,0}; }
  if (i == 0u){ bar[0] = 0u; bar[1] = 0u; }
}

// ---- prep: conv1d(pad1,k3) + relu + maxpool2 -> seq[84][256] ----
__global__ void k_seq(const float* __restrict__ x, const float* __restrict__ cw,
                      const float* __restrict__ cb, float* __restrict__ seq){
  const int q = blockIdx.x;      // 0..83
  const int b = threadIdx.x;     // 0..255
  float best = -1e30f;
#pragma unroll
  for (int ssub = 0; ssub < 2; ++ssub){
    int p = 2*q + ssub;
    float acc = cb[0];
#pragma unroll
    for (int k = 0; k < 3; ++k){
      int t = p - 1 + k;
      if (t >= 0 && t < 168){
        const float* xp = x + ((size_t)b*192 + t)*8;
#pragma unroll
        for (int i = 0; i < 8; ++i) acc = fmaf(xp[i], cw[i*3 + k], acc);
      }
    }
    acc  = fmaxf(acc, 0.0f);
    best = fmaxf(best, acc);
  }
  seq[(q<<8) + b] = best;
}

#define MFMA16(a,b,c) __builtin_amdgcn_mfma_f32_16x16x32_f16((a),(b),(c),0,0,0)

// ---- main persistent kernel: LDS-resident fp16 weights + MFMA ----
__global__ void __launch_bounds__(256) k_main(
    const float* __restrict__ Wih0, const float* __restrict__ Whh0,
    const float* __restrict__ bih0, const float* __restrict__ bhh0,
    const float* __restrict__ Wih1, const float* __restrict__ Whh1,
    const float* __restrict__ bih1, const float* __restrict__ bhh1,
    const float* __restrict__ fc_w, const float* __restrict__ fc_b,
    char* __restrict__ ws, float* __restrict__ out)
{
  extern __shared__ char smem_[];
  f16* lds = (f16*)smem_;            // [0,16384): Whh0  [16384,32768): Wih1  [32768,49152): Whh1

  const int tid  = threadIdx.x;
  const int blk  = blockIdx.x;       // owns hidden units 4*blk..4*blk+3
  const int j0   = blk << 2;
  const int l    = tid & 63;         // lane in wave
  const int wave = tid >> 6;
  const int u    = l >> 4;           // unit index within block / B-frag k-group
  const int c16  = l & 15;           // A-frag row / B-frag col

  // ---- pack the block's weight rows into LDS as MFMA A-fragments (once) ----
  {
    const int wrow = ((c16 & 3) << 10) + j0 + (c16 >> 2);  // tile row m -> matrix row g*1024+j0+u
    const int kloc = u << 3;
    const float* srcs[3] = {Whh0, Wih1, Whh1};
#pragma unroll
    for (int m = 0; m < 3; ++m){
      const float* srow = srcs[m] + (size_t)wrow * 1024;
      f16* dst = lds + m*16384;
      for (int cc = 0; cc < 8; ++cc){
        int c = (cc << 2) + wave;
        int col = (c << 5) + kloc;
        float4 a = *(const float4*)(srow + col);
        float4 b = *(const float4*)(srow + col + 4);
        f16x8 v;
        v[0]=(f16)a.x; v[1]=(f16)a.y; v[2]=(f16)a.z; v[3]=(f16)a.w;
        v[4]=(f16)b.x; v[5]=(f16)b.y; v[6]=(f16)b.z; v[7]=(f16)b.w;
        *(f16x8*)(dst + (((c << 6) + l) << 3)) = v;
      }
    }
  }
  __syncthreads();

  // ---- per-lane constants ----
  float bias0g[4], bias1g[4], wi0g[4];
#pragma unroll
  for (int g = 0; g < 4; ++g){
    int row = (g << 10) + j0 + u;
    bias0g[g] = bih0[row] + bhh0[row];
    bias1g[g] = bih1[row] + bhh1[row];
    wi0g[g]   = Wih0[row];
  }
  const float fcwu = fc_w[j0 + u] * 1.25f;
  const float fcb  = fc_b[0];

  int bcols[4];
#pragma unroll
  for (int t = 0; t < 4; ++t) bcols[t] = (wave << 6) + (t << 4) + c16;
  const int laneoff = (u << 11) + (c16 << 3) + (wave << 9);   // B-frag per-lane offset (halves)

  f16* H0 = (f16*)(ws + H0_OFF);     // regions of 262144 halves: [buf][hi/lo]
  f16* H1 = (f16*)(ws + H1_OFF);
  const float* seq = (const float*)(ws + SEQ_OFF);
  float* y_acc = (float*)(ws + YACC_OFF);
  unsigned* bcnt = (unsigned*)(ws + BAR_OFF);
  unsigned* bgate = bcnt + 1;

  const int khid = j0 + u;
  const int whioff = ((khid >> 3) << 11) + (khid & 7);        // h-write base (halves), + b*8

  float c0[4] = {0,0,0,0}, c1[4] = {0,0,0,0}, yprev[4] = {0,0,0,0};
  unsigned ep = 0;

#pragma unroll 1
  for (int s = 0; s < 107; ++s){
    const int src = s & 1, dst = src ^ 1;

    // ---- decoder input: y from previous step's fc accumulators ----
    if (s >= 84){
      const int tp = s - 84;
#pragma unroll
      for (int t = 0; t < 4; ++t) yprev[t] = fcb + y_acc[(tp << 8) + bcols[t]];
      if (blk == 0 && u == 0){
#pragma unroll
        for (int t = 0; t < 4; ++t) out[bcols[t]*24 + tp] = yprev[t];
      }
    }

    // ---- phase A: gates0 = Whh0 * (h0_hi + h0_lo)  [MFMA] ----
    const f16* a0hi = H0 + src*524288;
    const f16* a0lo = a0hi + 262144;
    f32x4 acc[4];
#pragma unroll
    for (int t = 0; t < 4; ++t) acc[t] = (f32x4){0.f,0.f,0.f,0.f};
#pragma unroll 2
    for (int c = 0; c < 32; ++c){
      f16x8 wf = *(const f16x8*)(lds + (((c << 6) + l) << 3));
      const f16* ph = a0hi + (c << 13) + laneoff;
      const f16* pl = a0lo + (c << 13) + laneoff;
#pragma unroll
      for (int t = 0; t < 4; ++t){
        f16x8 bh = *(const f16x8*)(ph + (t << 7));
        f16x8 bl = *(const f16x8*)(pl + (t << 7));
        acc[t] = MFMA16(wf, bh, acc[t]);
        acc[t] = MFMA16(wf, bl, acc[t]);
      }
    }
    float h0n[4];
    {
      f16* w0hi = H0 + dst*524288 + whioff;
      f16* w0lo = w0hi + 262144;
#pragma unroll
      for (int t = 0; t < 4; ++t){
        float xb = (s < 84) ? seq[(s << 8) + bcols[t]] : yprev[t];
        float pi = acc[t][0] + bias0g[0] + wi0g[0]*xb;
        float pf = acc[t][1] + bias0g[1] + wi0g[1]*xb;
        float pg = acc[t][2] + bias0g[2] + wi0g[2]*xb;
        float po = acc[t][3] + bias0g[3] + wi0g[3]*xb;
        c0[t]  = sigf(pf)*c0[t] + sigf(pi)*thf(pg);
        h0n[t] = sigf(po)*thf(c0[t]);
        f16 hi = (f16)h0n[t];
        f16 lo = (f16)(h0n[t] - (float)hi);
        w0hi[bcols[t] << 3] = hi;
        w0lo[bcols[t] << 3] = lo;
      }
    }
    ++ep; gbar(bcnt, bgate, ep);

    // ---- phase B: gates1 = Wih1*h0new + Whh1*h1  [MFMA] ----
    const f16* b0hi = H0 + dst*524288;
    const f16* b0lo = b0hi + 262144;
    const f16* b1hi = H1 + src*524288;
    const f16* b1lo = b1hi + 262144;
#pragma unroll
    for (int t = 0; t < 4; ++t) acc[t] = (f32x4){0.f,0.f,0.f,0.f};
#pragma unroll 2
    for (int c = 0; c < 32; ++c){
      f16x8 wa = *(const f16x8*)(lds + 16384 + (((c << 6) + l) << 3));
      f16x8 wb = *(const f16x8*)(lds + 32768 + (((c << 6) + l) << 3));
      const int co = (c << 13) + laneoff;
#pragma unroll
      for (int t = 0; t < 4; ++t){
        f16x8 x0h = *(const f16x8*)(b0hi + co + (t << 7));
        f16x8 x0l = *(const f16x8*)(b0lo + co + (t << 7));
        f16x8 x1h = *(const f16x8*)(b1hi + co + (t << 7));
        f16x8 x1l = *(const f16x8*)(b1lo + co + (t << 7));
        acc[t] = MFMA16(wa, x0h, acc[t]);
        acc[t] = MFMA16(wa, x0l, acc[t]);
        acc[t] = MFMA16(wb, x1h, acc[t]);
        acc[t] = MFMA16(wb, x1l, acc[t]);
      }
    }
    float h1n[4];
    {
      f16* w1hi = H1 + dst*524288 + whioff;
      f16* w1lo = w1hi + 262144;
#pragma unroll
      for (int t = 0; t < 4; ++t){
        float pi = acc[t][0] + bias1g[0];
        float pf = acc[t][1] + bias1g[1];
        float pg = acc[t][2] + bias1g[2];
        float po = acc[t][3] + bias1g[3];
        c1[t]  = sigf(pf)*c1[t] + sigf(pi)*thf(pg);
        h1n[t] = sigf(po)*thf(c1[t]);
        f16 hi = (f16)h1n[t];
        f16 lo = (f16)(h1n[t] - (float)hi);
        w1hi[bcols[t] << 3] = hi;
        w1lo[bcols[t] << 3] = lo;
      }
    }

    // ---- fc partials with exact JAX dropout (tau = s-83) ----
    if (s >= 83){
      const int tau = s - 83;
      uint2 fk = tf2x32(0u, 42u, 0u, (unsigned)tau);
#pragma unroll
      for (int t = 0; t < 4; ++t){
        unsigned n = ((unsigned)bcols[t] << 10) + (unsigned)khid;
        float v = drop_keep(fk, n) ? h1n[t]*fcwu : 0.f;
        v += __shfl_xor(v, 16, 64);
        v += __shfl_xor(v, 32, 64);
        if (u == 0) atomicAdd(y_acc + (tau << 8) + bcols[t], v);
      }
      ++ep; gbar(bcnt, bgate, ep);
    }
  }

  // tail: y_23
  if (blk == 0 && u == 0){
#pragma unroll
    for (int t = 0; t < 4; ++t) out[bcols[t]*24 + 23] = fcb + y_acc[(23 << 8) + bcols[t]];
  }
}

extern "C" void kernel_launch(void* const* d_in, const int* in_sizes, int n_in,
                              void* d_out, int out_size, void* d_ws, size_t ws_size,
                              hipStream_t stream)
{
  const float* x    = (const float*)d_in[0];
  const float* cw   = (const float*)d_in[1];
  const float* cb   = (const float*)d_in[2];
  const float* Wih0 = (const float*)d_in[3];
  const float* Whh0 = (const float*)d_in[4];
  const float* bih0 = (const float*)d_in[5];
  const float* bhh0 = (const float*)d_in[6];
  const float* Wih1 = (const float*)d_in[7];
  const float* Whh1 = (const float*)d_in[8];
  const float* bih1 = (const float*)d_in[9];
  const float* bhh1 = (const float*)d_in[10];
  const float* fc_w = (const float*)d_in[11];
  const float* fc_b = (const float*)d_in[12];
  float* out = (float*)d_out;
  char*  ws  = (char*)d_ws;

  hipLaunchKernelGGL(k_init, dim3(1030), dim3(256), 0, stream,
                     (uint4*)(ws + H0_OFF), (uint4*)(ws + YACC_OFF), (unsigned*)(ws + BAR_OFF));
  hipLaunchKernelGGL(k_seq,  dim3(84), dim3(256), 0, stream, x, cw, cb, (float*)(ws + SEQ_OFF));
  hipLaunchKernelGGL(k_main, dim3(256), dim3(256), 98304, stream,
                     Wih0, Whh0, bih0, bhh0, Wih1, Whh1, bih1, bhh1,
                     fc_w, fc_b, ws, out);
}

// Round 3
// 16071.919 us; speedup vs baseline: 4.7961x; 1.0870x over previous
//
#include <hip/hip_runtime.h>
#include <stdint.h>

typedef _Float16 f16;
typedef f16  f16x8 __attribute__((ext_vector_type(8)));
typedef float f32x4 __attribute__((ext_vector_type(4)));

// ---------------- ws layout (byte offsets) ----------------
// H0: h0 state, 2 bufs x [k/8][b][hi8|lo8] f16 = 2 MB (1 MB per buf)
// H1: same for h1                               = 2 MB
// SEQ:  [84][256] f32 encoder inputs
// YACC: [24][256] f32 fc accumulators (atomicAdd targets)
// FLAG: 256 x 128B-padded epoch flags (grid barrier)
#define H0_OFF   0u
#define H1_OFF   2097152u
#define SEQ_OFF  4194304u
#define YACC_OFF 4280320u
#define FLAG_OFF 4304896u

__device__ __forceinline__ unsigned rotl32(unsigned x, int d){ return (x<<d)|(x>>(32-d)); }

// Threefry-2x32, 20 rounds, exactly JAX's key schedule. (bit-exact, proven R1/R2)
__device__ __forceinline__ uint2 tf2x32(unsigned k0, unsigned k1, unsigned x0, unsigned x1){
  unsigned kx = k0 ^ k1 ^ 0x1BD11BDAu;
  x0 += k0; x1 += k1;
#define TFR(r) { x0 += x1; x1 = rotl32(x1,(r)); x1 ^= x0; }
  TFR(13) TFR(15) TFR(26) TFR(6)  x0 += k1; x1 += kx + 1u;
  TFR(17) TFR(29) TFR(16) TFR(24) x0 += kx; x1 += k0 + 2u;
  TFR(13) TFR(15) TFR(26) TFR(6)  x0 += k0; x1 += k1 + 3u;
  TFR(17) TFR(29) TFR(16) TFR(24) x0 += k1; x1 += kx + 4u;
  TFR(13) TFR(15) TFR(26) TFR(6)  x0 += kx; x1 += k0 + 5u;
#undef TFR
  return make_uint2(x0, x1);
}

__device__ __forceinline__ bool drop_keep(uint2 fk, unsigned n){
  uint2 o = tf2x32(fk.x, fk.y, 0u, n);
  unsigned bits = o.x ^ o.y;
  float u = __uint_as_float((bits >> 9) | 0x3f800000u) - 1.0f;
  return u < 0.8f;
}

__device__ __forceinline__ float sigf(float x){ return 1.0f/(1.0f + __expf(-x)); }
__device__ __forceinline__ float thf(float x){ return 1.0f - 2.0f/(__expf(2.0f*x) + 1.0f); }

// flag-array grid barrier: per-block padded flag, parallel polling.
__device__ __forceinline__ void gbar(unsigned* flags, unsigned e, int tid, int blk){
  __syncthreads();
  if (tid == 0){
    __threadfence();
    __hip_atomic_store(flags + blk*32, e, __ATOMIC_RELEASE, __HIP_MEMORY_SCOPE_AGENT);
  }
  if (tid < 256){
    unsigned* f = flags + tid*32;
    while (__hip_atomic_load(f, __ATOMIC_ACQUIRE, __HIP_MEMORY_SCOPE_AGENT) < e)
      __builtin_amdgcn_s_sleep(2);
  }
  __threadfence();
  __syncthreads();
}

// ---- prep: zero h buffers + y_acc + flags ----
__global__ void k_init(uint4* __restrict__ hz, uint4* __restrict__ yz, uint4* __restrict__ fz){
  unsigned i = blockIdx.x*256u + threadIdx.x;
  if (i < 262144u){ hz[i] = uint4{0,0,0,0}; }
  else if (i < 263680u){ yz[i - 262144u] = uint4{0,0,0,0}; }
  else if (i < 265728u){ fz[i - 263680u] = uint4{0,0,0,0}; }
}

// ---- prep: conv1d(pad1,k3) + relu + maxpool2 -> seq[84][256] ----
__global__ void k_seq(const float* __restrict__ x, const float* __restrict__ cw,
                      const float* __restrict__ cb, float* __restrict__ seq){
  const int q = blockIdx.x;      // 0..83
  const int b = threadIdx.x;     // 0..255
  float best = -1e30f;
#pragma unroll
  for (int ssub = 0; ssub < 2; ++ssub){
    int p = 2*q + ssub;
    float acc = cb[0];
#pragma unroll
    for (int k = 0; k < 3; ++k){
      int t = p - 1 + k;
      if (t >= 0 && t < 168){
        const float* xp = x + ((size_t)b*192 + t)*8;
#pragma unroll
        for (int i = 0; i < 8; ++i) acc = fmaf(xp[i], cw[i*3 + k], acc);
      }
    }
    acc  = fmaxf(acc, 0.0f);
    best = fmaxf(best, acc);
  }
  seq[(q<<8) + b] = best;
}

#define MFMA16(a,b,c) __builtin_amdgcn_mfma_f32_16x16x32_f16((a),(b),(c),0,0,0)

// ---- main persistent kernel: 1024 threads (16 waves), LDS fp16 weights + MFMA ----
__global__ void __launch_bounds__(1024) k_main(
    const float* __restrict__ Wih0, const float* __restrict__ Whh0,
    const float* __restrict__ bih0, const float* __restrict__ bhh0,
    const float* __restrict__ Wih1, const float* __restrict__ Whh1,
    const float* __restrict__ bih1, const float* __restrict__ bhh1,
    const float* __restrict__ fc_w, const float* __restrict__ fc_b,
    char* __restrict__ ws, float* __restrict__ out)
{
  extern __shared__ char smem_[];
  f16* lds = (f16*)smem_;     // halves: [0,16384) Whh0 | [16384,32768) Wih1 | [32768,49152) Whh1

  const int tid  = threadIdx.x;
  const int blk  = blockIdx.x;       // owns hidden units 4*blk..4*blk+3
  const int j0   = blk << 2;
  const int l    = tid & 63;
  const int w16  = tid >> 6;         // wave 0..15, owns batch cols w16*16..+16
  const int u    = l >> 4;           // k-group of B-frag / unit index
  const int c16  = l & 15;           // A row-group / batch col within tile
  const int bcol = (w16 << 4) + c16;

  // ---- pack block's weight rows into LDS as MFMA A-fragments (once) ----
  {
    const int wrow = ((c16 & 3) << 10) + j0 + (c16 >> 2);
    const int kloc = u << 3;
    const float* srcs[3] = {Whh0, Wih1, Whh1};
#pragma unroll
    for (int m = 0; m < 3; ++m){
      const float* srow = srcs[m] + (size_t)wrow * 1024;
      f16* dst = lds + m*16384;
#pragma unroll
      for (int cc = 0; cc < 2; ++cc){
        int c = (cc << 4) + w16;
        int col = (c << 5) + kloc;
        float4 a = *(const float4*)(srow + col);
        float4 b = *(const float4*)(srow + col + 4);
        f16x8 v;
        v[0]=(f16)a.x; v[1]=(f16)a.y; v[2]=(f16)a.z; v[3]=(f16)a.w;
        v[4]=(f16)b.x; v[5]=(f16)b.y; v[6]=(f16)b.z; v[7]=(f16)b.w;
        *(f16x8*)(dst + (((c << 6) + l) << 3)) = v;
      }
    }
  }
  __syncthreads();

  // ---- per-lane constants ----
  float bias0g[4], bias1g[4], wi0g[4];
#pragma unroll
  for (int g = 0; g < 4; ++g){
    int row = (g << 10) + j0 + u;
    bias0g[g] = bih0[row] + bhh0[row];
    bias1g[g] = bih1[row] + bhh1[row];
    wi0g[g]   = Wih0[row];
  }
  const int   khid = j0 + u;
  const float fcwu = fc_w[khid] * 1.25f;
  const float fcb  = fc_b[0];

  const int lanebase = (u << 12) + (bcol << 4);               // B-frag read base (halves)
  const int wbase    = ((khid >> 3) << 12) + (bcol << 4) + (khid & 7);  // h-write base

  f16* H0 = (f16*)(ws + H0_OFF);     // per-buf 524288 halves
  f16* H1 = (f16*)(ws + H1_OFF);
  const float* seq = (const float*)(ws + SEQ_OFF);
  float* y_acc = (float*)(ws + YACC_OFF);
  unsigned* flags = (unsigned*)(ws + FLAG_OFF);

  float c0 = 0.f, c1 = 0.f, yprev = 0.f;
  unsigned ep = 0;

#pragma unroll 1
  for (int s = 0; s < 107; ++s){
    const int src = s & 1, dst = src ^ 1;

    // ---- decoder input: y from previous step's fc accumulators ----
    if (s >= 84){
      const int tp = s - 84;
      yprev = fcb + y_acc[(tp << 8) + bcol];
      if (blk == 0 && u == 0) out[bcol*24 + tp] = yprev;
    }

    // ---- phase A: gates0 = Whh0 * (h0_hi + h0_lo)  [MFMA] ----
    {
      const f16* a0 = H0 + src*524288 + lanebase;
      f32x4 acc = (f32x4){0.f,0.f,0.f,0.f};
#pragma unroll 8
      for (int c = 0; c < 32; ++c){
        f16x8 wf = *(const f16x8*)(lds + (((c << 6) + l) << 3));
        f16x8 bh = *(const f16x8*)(a0 + (c << 14));
        f16x8 bl = *(const f16x8*)(a0 + (c << 14) + 8);
        acc = MFMA16(wf, bh, acc);
        acc = MFMA16(wf, bl, acc);
      }
      float xb = (s < 84) ? seq[(s << 8) + bcol] : yprev;
      float pi = acc[0] + bias0g[0] + wi0g[0]*xb;
      float pf = acc[1] + bias0g[1] + wi0g[1]*xb;
      float pg = acc[2] + bias0g[2] + wi0g[2]*xb;
      float po = acc[3] + bias0g[3] + wi0g[3]*xb;
      c0 = sigf(pf)*c0 + sigf(pi)*thf(pg);
      float h0n = sigf(po)*thf(c0);
      f16 hi = (f16)h0n;
      f16 lo = (f16)(h0n - (float)hi);
      f16* w = H0 + dst*524288 + wbase;
      w[0] = hi; w[8] = lo;
    }
    ++ep; gbar(flags, ep, tid, blk);

    // ---- phase B: gates1 = Wih1*h0new + Whh1*h1  [MFMA] ----
    float h1n;
    {
      const f16* b0 = H0 + dst*524288 + lanebase;
      const f16* b1 = H1 + src*524288 + lanebase;
      f32x4 acc = (f32x4){0.f,0.f,0.f,0.f};
#pragma unroll 4
      for (int c = 0; c < 32; ++c){
        f16x8 wa = *(const f16x8*)(lds + 16384 + (((c << 6) + l) << 3));
        f16x8 wb = *(const f16x8*)(lds + 32768 + (((c << 6) + l) << 3));
        f16x8 x0h = *(const f16x8*)(b0 + (c << 14));
        f16x8 x0l = *(const f16x8*)(b0 + (c << 14) + 8);
        f16x8 x1h = *(const f16x8*)(b1 + (c << 14));
        f16x8 x1l = *(const f16x8*)(b1 + (c << 14) + 8);
        acc = MFMA16(wa, x0h, acc);
        acc = MFMA16(wa, x0l, acc);
        acc = MFMA16(wb, x1h, acc);
        acc = MFMA16(wb, x1l, acc);
      }
      float pi = acc[0] + bias1g[0];
      float pf = acc[1] + bias1g[1];
      float pg = acc[2] + bias1g[2];
      float po = acc[3] + bias1g[3];
      c1 = sigf(pf)*c1 + sigf(pi)*thf(pg);
      h1n = sigf(po)*thf(c1);
      f16 hi = (f16)h1n;
      f16 lo = (f16)(h1n - (float)hi);
      f16* w = H1 + dst*524288 + wbase;
      w[0] = hi; w[8] = lo;
    }

    // ---- fc partials with exact JAX dropout (tau = s-83) ----
    if (s >= 83){
      const int tau = s - 83;
      uint2 fk = tf2x32(0u, 42u, 0u, (unsigned)tau);
      unsigned n = ((unsigned)bcol << 10) + (unsigned)khid;
      float v = drop_keep(fk, n) ? h1n*fcwu : 0.f;
      v += __shfl_xor(v, 16, 64);
      v += __shfl_xor(v, 32, 64);
      if (u == 0) atomicAdd(y_acc + (tau << 8) + bcol, v);
      ++ep; gbar(flags, ep, tid, blk);
    }
  }

  // tail: y_23
  if (blk == 0 && u == 0) out[bcol*24 + 23] = fcb + y_acc[(23 << 8) + bcol];
}

extern "C" void kernel_launch(void* const* d_in, const int* in_sizes, int n_in,
                              void* d_out, int out_size, void* d_ws, size_t ws_size,
                              hipStream_t stream)
{
  const float* x    = (const float*)d_in[0];
  const float* cw   = (const float*)d_in[1];
  const float* cb   = (const float*)d_in[2];
  const float* Wih0 = (const float*)d_in[3];
  const float* Whh0 = (const float*)d_in[4];
  const float* bih0 = (const float*)d_in[5];
  const float* bhh0 = (const float*)d_in[6];
  const float* Wih1 = (const float*)d_in[7];
  const float* Whh1 = (const float*)d_in[8];
  const float* bih1 = (const float*)d_in[9];
  const float* bhh1 = (const float*)d_in[10];
  const float* fc_w = (const float*)d_in[11];
  const float* fc_b = (const float*)d_in[12];
  float* out = (float*)d_out;
  char*  ws  = (char*)d_ws;

  hipLaunchKernelGGL(k_init, dim3(1038), dim3(256), 0, stream,
                     (uint4*)(ws + H0_OFF), (uint4*)(ws + YACC_OFF), (uint4*)(ws + FLAG_OFF));
  hipLaunchKernelGGL(k_seq,  dim3(84), dim3(256), 0, stream, x, cw, cb, (float*)(ws + SEQ_OFF));
  hipLaunchKernelGGL(k_main, dim3(256), dim3(1024), 98304, stream,
                     Wih0, Whh0, bih0, bhh0, Wih1, Whh1, bih1, bhh1,
                     fc_w, fc_b, ws, out);
}

// Round 4
// 8728.469 us; speedup vs baseline: 8.8312x; 1.8413x over previous
//
#include <hip/hip_runtime.h>
#include <stdint.h>

typedef _Float16 f16;
typedef f16  f16x8 __attribute__((ext_vector_type(8)));
typedef float f32x4 __attribute__((ext_vector_type(4)));

// ---------------- ws layout (byte offsets) ----------------
#define H0_OFF   0u
#define H1_OFF   2097152u
#define SEQ_OFF  4194304u
#define YACC_OFF 4280320u
#define FLAG_OFF 4304896u

__device__ __forceinline__ unsigned rotl32(unsigned x, int d){ return (x<<d)|(x>>(32-d)); }

// Threefry-2x32, 20 rounds, exactly JAX's key schedule. (bit-exact, proven R1-R3)
__device__ __forceinline__ uint2 tf2x32(unsigned k0, unsigned k1, unsigned x0, unsigned x1){
  unsigned kx = k0 ^ k1 ^ 0x1BD11BDAu;
  x0 += k0; x1 += k1;
#define TFR(r) { x0 += x1; x1 = rotl32(x1,(r)); x1 ^= x0; }
  TFR(13) TFR(15) TFR(26) TFR(6)  x0 += k1; x1 += kx + 1u;
  TFR(17) TFR(29) TFR(16) TFR(24) x0 += kx; x1 += k0 + 2u;
  TFR(13) TFR(15) TFR(26) TFR(6)  x0 += k0; x1 += k1 + 3u;
  TFR(17) TFR(29) TFR(16) TFR(24) x0 += k1; x1 += kx + 4u;
  TFR(13) TFR(15) TFR(26) TFR(6)  x0 += kx; x1 += k0 + 5u;
#undef TFR
  return make_uint2(x0, x1);
}

__device__ __forceinline__ bool drop_keep(uint2 fk, unsigned n){
  uint2 o = tf2x32(fk.x, fk.y, 0u, n);
  unsigned bits = o.x ^ o.y;
  float u = __uint_as_float((bits >> 9) | 0x3f800000u) - 1.0f;
  return u < 0.8f;
}

__device__ __forceinline__ float sigf(float x){ return 1.0f/(1.0f + __expf(-x)); }
__device__ __forceinline__ float thf(float x){ return 1.0f - 2.0f/(__expf(2.0f*x) + 1.0f); }

// ---- L2-bypassing (LLC-coherent) accessors: no wbl2/inv needed for visibility ----
__device__ __forceinline__ void st_short_sc(void* p, unsigned v){
  asm volatile("global_store_short %0, %1, off sc0 sc1" :: "v"(p), "v"(v) : "memory");
}
__device__ __forceinline__ void st_dword_sc(void* p, unsigned v){
  asm volatile("global_store_dword %0, %1, off sc0 sc1" :: "v"(p), "v"(v) : "memory");
}
__device__ __forceinline__ unsigned ld_dword_sc(const void* p){
  unsigned r;
  asm volatile("global_load_dword %0, %1, off sc0 sc1\n\ts_waitcnt vmcnt(0)"
               : "=v"(r) : "v"(p) : "memory");
  return r;
}

// grid barrier: sc1 writes are already at the coherence point, so release needs
// only vmcnt-drain + flag store; acquire = one L2-invalidate (no writeback walk).
__device__ __forceinline__ void gbar(unsigned* flags, unsigned e, int tid, int blk){
  asm volatile("s_waitcnt vmcnt(0)" ::: "memory");
  __syncthreads();
  if (tid == 0) st_dword_sc(flags + blk*32, e);
  if (tid < 256){
    unsigned* f = flags + tid*32;
    while (ld_dword_sc(f) < e) __builtin_amdgcn_s_sleep(1);
  }
  __syncthreads();
  __builtin_amdgcn_fence(__ATOMIC_ACQUIRE, "agent");   // buffer_inv: drop stale L2/L1 lines
  __builtin_amdgcn_sched_barrier(0);
}

// ---- prep: zero h buffers + y_acc + flags ----
__global__ void k_init(uint4* __restrict__ hz, uint4* __restrict__ yz, uint4* __restrict__ fz){
  unsigned i = blockIdx.x*256u + threadIdx.x;
  if (i < 262144u){ hz[i] = uint4{0,0,0,0}; }
  else if (i < 263680u){ yz[i - 262144u] = uint4{0,0,0,0}; }
  else if (i < 265728u){ fz[i - 263680u] = uint4{0,0,0,0}; }
}

// ---- prep: conv1d(pad1,k3) + relu + maxpool2 -> seq[84][256] ----
__global__ void k_seq(const float* __restrict__ x, const float* __restrict__ cw,
                      const float* __restrict__ cb, float* __restrict__ seq){
  const int q = blockIdx.x;
  const int b = threadIdx.x;
  float best = -1e30f;
#pragma unroll
  for (int ssub = 0; ssub < 2; ++ssub){
    int p = 2*q + ssub;
    float acc = cb[0];
#pragma unroll
    for (int k = 0; k < 3; ++k){
      int t = p - 1 + k;
      if (t >= 0 && t < 168){
        const float* xp = x + ((size_t)b*192 + t)*8;
#pragma unroll
        for (int i = 0; i < 8; ++i) acc = fmaf(xp[i], cw[i*3 + k], acc);
      }
    }
    acc  = fmaxf(acc, 0.0f);
    best = fmaxf(best, acc);
  }
  seq[(q<<8) + b] = best;
}

#define MFMA16(a,b,c) __builtin_amdgcn_mfma_f32_16x16x32_f16((a),(b),(c),0,0,0)

// ---- main persistent kernel: 1024 threads (16 waves), LDS fp16 weights + MFMA ----
__global__ void __launch_bounds__(1024) k_main(
    const float* __restrict__ Wih0, const float* __restrict__ Whh0,
    const float* __restrict__ bih0, const float* __restrict__ bhh0,
    const float* __restrict__ Wih1, const float* __restrict__ Whh1,
    const float* __restrict__ bih1, const float* __restrict__ bhh1,
    const float* __restrict__ fc_w, const float* __restrict__ fc_b,
    char* __restrict__ ws, float* __restrict__ out)
{
  extern __shared__ char smem_[];
  f16* lds = (f16*)smem_;     // halves: [0,16384) Whh0 | [16384,32768) Wih1 | [32768,49152) Whh1

  const int tid  = threadIdx.x;
  const int blk  = blockIdx.x;       // owns hidden units 4*blk..4*blk+3
  const int j0   = blk << 2;
  const int l    = tid & 63;
  const int w16  = tid >> 6;         // wave 0..15, owns batch cols w16*16..+16
  const int u    = l >> 4;
  const int c16  = l & 15;
  const int bcol = (w16 << 4) + c16;

  // ---- pack block's weight rows into LDS as MFMA A-fragments (once) ----
  {
    const int wrow = ((c16 & 3) << 10) + j0 + (c16 >> 2);
    const int kloc = u << 3;
    const float* srcs[3] = {Whh0, Wih1, Whh1};
#pragma unroll
    for (int m = 0; m < 3; ++m){
      const float* srow = srcs[m] + (size_t)wrow * 1024;
      f16* dst = lds + m*16384;
#pragma unroll
      for (int cc = 0; cc < 2; ++cc){
        int c = (cc << 4) + w16;
        int col = (c << 5) + kloc;
        float4 a = *(const float4*)(srow + col);
        float4 b = *(const float4*)(srow + col + 4);
        f16x8 v;
        v[0]=(f16)a.x; v[1]=(f16)a.y; v[2]=(f16)a.z; v[3]=(f16)a.w;
        v[4]=(f16)b.x; v[5]=(f16)b.y; v[6]=(f16)b.z; v[7]=(f16)b.w;
        *(f16x8*)(dst + (((c << 6) + l) << 3)) = v;
      }
    }
  }
  __syncthreads();

  // ---- per-lane constants ----
  float bias0g[4], bias1g[4], wi0g[4];
#pragma unroll
  for (int g = 0; g < 4; ++g){
    int row = (g << 10) + j0 + u;
    bias0g[g] = bih0[row] + bhh0[row];
    bias1g[g] = bih1[row] + bhh1[row];
    wi0g[g]   = Wih0[row];
  }
  const int   khid = j0 + u;
  const float fcwu = fc_w[khid] * 1.25f;
  const float fcb  = fc_b[0];

  const int lanebase = (u << 12) + (bcol << 4);
  const int wbase    = ((khid >> 3) << 12) + (bcol << 4) + (khid & 7);

  f16* H0 = (f16*)(ws + H0_OFF);
  f16* H1 = (f16*)(ws + H1_OFF);
  const float* seq = (const float*)(ws + SEQ_OFF);
  float* y_acc = (float*)(ws + YACC_OFF);
  unsigned* flags = (unsigned*)(ws + FLAG_OFF);

  float c0 = 0.f, c1 = 0.f, yprev = 0.f;
  unsigned ep = 0;

#pragma unroll 1
  for (int s = 0; s < 107; ++s){
    const int src = s & 1, dst = src ^ 1;

    // ---- decoder input: y from previous step's fc accumulators ----
    if (s >= 84){
      const int tp = s - 84;
      yprev = fcb + y_acc[(tp << 8) + bcol];
      if (blk == 0 && u == 0) out[bcol*24 + tp] = yprev;
    }

    // ---- phase A: gates0 = Whh0 * (h0_hi + h0_lo)  [MFMA] ----
    {
      const f16* a0 = H0 + src*524288 + lanebase;
      f32x4 acc = (f32x4){0.f,0.f,0.f,0.f};
#pragma unroll 8
      for (int c = 0; c < 32; ++c){
        f16x8 wf = *(const f16x8*)(lds + (((c << 6) + l) << 3));
        f16x8 bh = *(const f16x8*)(a0 + (c << 14));
        f16x8 bl = *(const f16x8*)(a0 + (c << 14) + 8);
        acc = MFMA16(wf, bh, acc);
        acc = MFMA16(wf, bl, acc);
      }
      float xb = (s < 84) ? seq[(s << 8) + bcol] : yprev;
      float pi = acc[0] + bias0g[0] + wi0g[0]*xb;
      float pf = acc[1] + bias0g[1] + wi0g[1]*xb;
      float pg = acc[2] + bias0g[2] + wi0g[2]*xb;
      float po = acc[3] + bias0g[3] + wi0g[3]*xb;
      c0 = sigf(pf)*c0 + sigf(pi)*thf(pg);
      float h0n = sigf(po)*thf(c0);
      f16 hi = (f16)h0n;
      f16 lo = (f16)(h0n - (float)hi);
      f16* w = H0 + dst*524288 + wbase;
      st_short_sc(w,     (unsigned)__builtin_bit_cast(unsigned short, hi));
      st_short_sc(w + 8, (unsigned)__builtin_bit_cast(unsigned short, lo));
    }
    ++ep; gbar(flags, ep, tid, blk);

    // ---- phase B: gates1 = Wih1*h0new + Whh1*h1  [MFMA] ----
    float h1n;
    {
      const f16* b0 = H0 + dst*524288 + lanebase;
      const f16* b1 = H1 + src*524288 + lanebase;
      f32x4 acc = (f32x4){0.f,0.f,0.f,0.f};
#pragma unroll 4
      for (int c = 0; c < 32; ++c){
        f16x8 wa = *(const f16x8*)(lds + 16384 + (((c << 6) + l) << 3));
        f16x8 wb = *(const f16x8*)(lds + 32768 + (((c << 6) + l) << 3));
        f16x8 x0h = *(const f16x8*)(b0 + (c << 14));
        f16x8 x0l = *(const f16x8*)(b0 + (c << 14) + 8);
        f16x8 x1h = *(const f16x8*)(b1 + (c << 14));
        f16x8 x1l = *(const f16x8*)(b1 + (c << 14) + 8);
        acc = MFMA16(wa, x0h, acc);
        acc = MFMA16(wa, x0l, acc);
        acc = MFMA16(wb, x1h, acc);
        acc = MFMA16(wb, x1l, acc);
      }
      float pi = acc[0] + bias1g[0];
      float pf = acc[1] + bias1g[1];
      float pg = acc[2] + bias1g[2];
      float po = acc[3] + bias1g[3];
      c1 = sigf(pf)*c1 + sigf(pi)*thf(pg);
      h1n = sigf(po)*thf(c1);
      f16 hi = (f16)h1n;
      f16 lo = (f16)(h1n - (float)hi);
      f16* w = H1 + dst*524288 + wbase;
      st_short_sc(w,     (unsigned)__builtin_bit_cast(unsigned short, hi));
      st_short_sc(w + 8, (unsigned)__builtin_bit_cast(unsigned short, lo));
    }

    // ---- fc partials with exact JAX dropout (tau = s-83) ----
    if (s >= 83){
      const int tau = s - 83;
      uint2 fk = tf2x32(0u, 42u, 0u, (unsigned)tau);
      unsigned n = ((unsigned)bcol << 10) + (unsigned)khid;
      float v = drop_keep(fk, n) ? h1n*fcwu : 0.f;
      v += __shfl_xor(v, 16, 64);
      v += __shfl_xor(v, 32, 64);
      if (u == 0) atomicAdd(y_acc + (tau << 8) + bcol, v);
      ++ep; gbar(flags, ep, tid, blk);
    }
  }

  // tail: y_23
  if (blk == 0 && u == 0) out[bcol*24 + 23] = fcb + y_acc[(23 << 8) + bcol];
}

extern "C" void kernel_launch(void* const* d_in, const int* in_sizes, int n_in,
                              void* d_out, int out_size, void* d_ws, size_t ws_size,
                              hipStream_t stream)
{
  const float* x    = (const float*)d_in[0];
  const float* cw   = (const float*)d_in[1];
  const float* cb   = (const float*)d_in[2];
  const float* Wih0 = (const float*)d_in[3];
  const float* Whh0 = (const float*)d_in[4];
  const float* bih0 = (const float*)d_in[5];
  const float* bhh0 = (const float*)d_in[6];
  const float* Wih1 = (const float*)d_in[7];
  const float* Whh1 = (const float*)d_in[8];
  const float* bih1 = (const float*)d_in[9];
  const float* bhh1 = (const float*)d_in[10];
  const float* fc_w = (const float*)d_in[11];
  const float* fc_b = (const float*)d_in[12];
  float* out = (float*)d_out;
  char*  ws  = (char*)d_ws;

  hipLaunchKernelGGL(k_init, dim3(1038), dim3(256), 0, stream,
                     (uint4*)(ws + H0_OFF), (uint4*)(ws + YACC_OFF), (uint4*)(ws + FLAG_OFF));
  hipLaunchKernelGGL(k_seq,  dim3(84), dim3(256), 0, stream, x, cw, cb, (float*)(ws + SEQ_OFF));
  hipLaunchKernelGGL(k_main, dim3(256), dim3(1024), 98304, stream,
                     Wih0, Whh0, bih0, bhh0, Wih1, Whh1, bih1, bhh1,
                     fc_w, fc_b, ws, out);
}

// Round 6
// 7130.568 us; speedup vs baseline: 10.8102x; 1.2241x over previous
//
#include <hip/hip_runtime.h>
#include <stdint.h>

typedef _Float16 f16;
typedef f16  f16x8 __attribute__((ext_vector_type(8)));
typedef float f32x4 __attribute__((ext_vector_type(4)));
typedef unsigned u32x4 __attribute__((ext_vector_type(4)));

// ---------------- ws layout (byte offsets) ----------------
// H0/H1: 2 bufs x [k/8][b][hi8|lo8] f16 (1 MB per buf)
// WHH1: fp16 MFMA A-fragments of Whh1, [blk128][frag64][lane64][8] = 8 MB
// SEQ [84][256] f32 | YACC [24][256] f32 | FLAG 128 x 128B
#define H0_OFF    0u
#define H1_OFF    2097152u
#define WHH1_OFF  4194304u
#define SEQ_OFF   12582912u
#define YACC_OFF  12668928u
#define FLAG_OFF  12693504u

__device__ __forceinline__ unsigned rotl32(unsigned x, int d){ return (x<<d)|(x>>(32-d)); }

// Threefry-2x32, 20 rounds, exactly JAX's key schedule. (bit-exact, proven R1-R4)
__device__ __forceinline__ uint2 tf2x32(unsigned k0, unsigned k1, unsigned x0, unsigned x1){
  unsigned kx = k0 ^ k1 ^ 0x1BD11BDAu;
  x0 += k0; x1 += k1;
#define TFR(r) { x0 += x1; x1 = rotl32(x1,(r)); x1 ^= x0; }
  TFR(13) TFR(15) TFR(26) TFR(6)  x0 += k1; x1 += kx + 1u;
  TFR(17) TFR(29) TFR(16) TFR(24) x0 += kx; x1 += k0 + 2u;
  TFR(13) TFR(15) TFR(26) TFR(6)  x0 += k0; x1 += k1 + 3u;
  TFR(17) TFR(29) TFR(16) TFR(24) x0 += k1; x1 += kx + 4u;
  TFR(13) TFR(15) TFR(26) TFR(6)  x0 += kx; x1 += k0 + 5u;
#undef TFR
  return make_uint2(x0, x1);
}

__device__ __forceinline__ bool drop_keep(uint2 fk, unsigned n){
  uint2 o = tf2x32(fk.x, fk.y, 0u, n);
  unsigned bits = o.x ^ o.y;
  float u = __uint_as_float((bits >> 9) | 0x3f800000u) - 1.0f;
  return u < 0.8f;
}

__device__ __forceinline__ float sigf(float x){ return 1.0f/(1.0f + __expf(-x)); }
__device__ __forceinline__ float thf(float x){ return 1.0f - 2.0f/(__expf(2.0f*x) + 1.0f); }

// ---- LLC-coherent (L2-bypassing) accessors ----
__device__ __forceinline__ void st_dword_sc(void* p, unsigned v){
  asm volatile("global_store_dword %0, %1, off sc0 sc1" :: "v"(p), "v"(v) : "memory");
}
__device__ __forceinline__ void st_dwordx4_sc(void* p, u32x4 v){
  asm volatile("global_store_dwordx4 %0, %1, off sc0 sc1" :: "v"(p), "v"(v) : "memory");
}
__device__ __forceinline__ unsigned ld_dword_sc(const void* p){
  unsigned r;
  asm volatile("global_load_dword %0, %1, off sc0 sc1\n\ts_waitcnt vmcnt(0)"
               : "=v"(r) : "v"(p) : "memory");
  return r;
}

// grid barrier (proven R4): vmcnt-drain + sc1 flag store; poll; one L2-inv on acquire.
__device__ __forceinline__ void gbar(unsigned* flags, unsigned e, int tid, int blk){
  asm volatile("s_waitcnt vmcnt(0)" ::: "memory");
  __syncthreads();
  if (tid == 0) st_dword_sc(flags + blk*32, e);
  if (tid < 128){
    unsigned* f = flags + tid*32;
    while (ld_dword_sc(f) < e) __builtin_amdgcn_s_sleep(1);
  }
  __syncthreads();
  __builtin_amdgcn_fence(__ATOMIC_ACQUIRE, "agent");
  __builtin_amdgcn_sched_barrier(0);
}

// ---- prep: zero h buffers + y_acc + flags ----
__global__ void k_init(uint4* __restrict__ hz, uint4* __restrict__ yz, uint4* __restrict__ fz){
  unsigned i = blockIdx.x*256u + threadIdx.x;
  if (i < 262144u){ hz[i] = uint4{0,0,0,0}; }
  else if (i < 263680u){ yz[i - 262144u] = uint4{0,0,0,0}; }
  else if (i < 264704u){ fz[i - 263680u] = uint4{0,0,0,0}; }
}

// ---- prep: conv1d(pad1,k3) + relu + maxpool2 -> seq[84][256] ----
__global__ void k_seq(const float* __restrict__ x, const float* __restrict__ cw,
                      const float* __restrict__ cb, float* __restrict__ seq){
  const int q = blockIdx.x;
  const int b = threadIdx.x;
  float best = -1e30f;
#pragma unroll
  for (int ssub = 0; ssub < 2; ++ssub){
    int p = 2*q + ssub;
    float acc = cb[0];
#pragma unroll
    for (int k = 0; k < 3; ++k){
      int t = p - 1 + k;
      if (t >= 0 && t < 168){
        const float* xp = x + ((size_t)b*192 + t)*8;
#pragma unroll
        for (int i = 0; i < 8; ++i) acc = fmaf(xp[i], cw[i*3 + k], acc);
      }
    }
    acc  = fmaxf(acc, 0.0f);
    best = fmaxf(best, acc);
  }
  seq[(q<<8) + b] = best;
}

// ---- prep: pack Whh1 (fp32 [4096][1024]) into fp16 MFMA A-frags per block ----
// frag f = iter*2 + tile; row r=l&15 -> unit u=tile*4+(r>>2), gate g=r&3
__global__ void __launch_bounds__(1024) k_wpack(const float* __restrict__ Whh1, f16* __restrict__ dst){
  const int blk = blockIdx.x;        // 0..127
  const int tid = threadIdx.x;
  const int l   = tid & 63;
  const int w   = tid >> 6;
  const int j0  = blk << 3;
#pragma unroll
  for (int fi = 0; fi < 4; ++fi){
    const int f = (w << 2) + fi;
    const int c = f >> 1, T = f & 1;
    const int r = l & 15;
    const int u = (T << 2) + (r >> 2);
    const int g = r & 3;
    const float* src = Whh1 + (((size_t)((g << 10) + j0 + u)) << 10) + (c << 5) + ((l >> 4) << 3);
    float4 a = *(const float4*)src;
    float4 b = *(const float4*)(src + 4);
    f16x8 v;
    v[0]=(f16)a.x; v[1]=(f16)a.y; v[2]=(f16)a.z; v[3]=(f16)a.w;
    v[4]=(f16)b.x; v[5]=(f16)b.y; v[6]=(f16)b.z; v[7]=(f16)b.w;
    *(f16x8*)(dst + ((size_t)blk << 15) + (f << 9) + (l << 3)) = v;
  }
}

#define MFMA16(a,b,c) __builtin_amdgcn_mfma_f32_16x16x32_f16((a),(b),(c),0,0,0)

// ---- main persistent kernel: 128 blocks x 1024 threads, U=8 units/block ----
__global__ void __launch_bounds__(1024) k_main(
    const float* __restrict__ Wih0, const float* __restrict__ Whh0,
    const float* __restrict__ bih0, const float* __restrict__ bhh0,
    const float* __restrict__ Wih1, const float* __restrict__ Whh1,
    const float* __restrict__ bih1, const float* __restrict__ bhh1,
    const float* __restrict__ fc_w, const float* __restrict__ fc_b,
    char* __restrict__ ws, float* __restrict__ out)
{
  extern __shared__ char smem_[];
  f16* lds = (f16*)smem_;          // halves: [0,32768) Whh0 frags | [32768,65536) Wih1 frags
  f16* stage = lds + 65536;        // [65536,69632): [256 b][hi8|lo8] staging

  const int tid  = threadIdx.x;
  const int blk  = blockIdx.x;     // owns hidden units 8*blk..8*blk+7
  const int j0   = blk << 3;
  const int l    = tid & 63;
  const int w16  = tid >> 6;       // wave 0..15, batch cols w16*16..+16
  const int q    = l >> 4;         // operand k-group / unit (tile0: q, tile1: q+4)
  const int c16  = l & 15;
  const int bcol = (w16 << 4) + c16;

  // ---- pack Whh0, Wih1 rows into LDS as MFMA A-frags (once) ----
  {
    const float* srcs[2] = {Whh0, Wih1};
#pragma unroll
    for (int m = 0; m < 2; ++m){
#pragma unroll
      for (int fi = 0; fi < 4; ++fi){
        const int f = (w16 << 2) + fi;
        const int c = f >> 1, T = f & 1;
        const int r = c16;
        const int uu = (T << 2) + (r >> 2);
        const int g = r & 3;
        const float* src = srcs[m] + (((size_t)((g << 10) + j0 + uu)) << 10) + (c << 5) + (q << 3);
        float4 a = *(const float4*)src;
        float4 b = *(const float4*)(src + 4);
        f16x8 v;
        v[0]=(f16)a.x; v[1]=(f16)a.y; v[2]=(f16)a.z; v[3]=(f16)a.w;
        v[4]=(f16)b.x; v[5]=(f16)b.y; v[6]=(f16)b.z; v[7]=(f16)b.w;
        *(f16x8*)(lds + m*32768 + (f << 9) + (l << 3)) = v;
      }
    }
  }
  __syncthreads();

  // ---- per-lane constants (units q and q+4) ----
  float bias0t[2][4], bias1t[2][4], wi0t[2][4];
#pragma unroll
  for (int t = 0; t < 2; ++t){
    const int uu = j0 + q + t*4;
#pragma unroll
    for (int g = 0; g < 4; ++g){
      int row = (g << 10) + uu;
      bias0t[t][g] = bih0[row] + bhh0[row];
      bias1t[t][g] = bih1[row] + bhh1[row];
      wi0t[t][g]   = Wih0[row];
    }
  }
  const float fcw0 = fc_w[j0 + q] * 1.25f;
  const float fcw1 = fc_w[j0 + q + 4] * 1.25f;
  const float fcb  = fc_b[0];

  const int base_h = (q << 12) + (bcol << 4);   // B-frag per-lane offset (halves), iter stride 16384

  f16* H0 = (f16*)(ws + H0_OFF);   // per-buf 524288 halves
  f16* H1 = (f16*)(ws + H1_OFF);
  const f16* whh1f = (const f16*)(ws + WHH1_OFF) + ((size_t)blk << 15);
  const float* seq = (const float*)(ws + SEQ_OFF);
  float* y_acc = (float*)(ws + YACC_OFF);
  unsigned* flags = (unsigned*)(ws + FLAG_OFF);

  float c0[2] = {0,0}, c1[2] = {0,0};
  float yprev = 0.f;
  unsigned ep = 0;

#pragma unroll 1
  for (int s = 0; s < 107; ++s){
    const int src = s & 1, dst = src ^ 1;

    if (s >= 84){
      const int tp = s - 84;
      yprev = fcb + y_acc[(tp << 8) + bcol];
      if (blk == 0 && q == 0) out[bcol*24 + tp] = yprev;
    }

    // ---- phase A: gates0 = Whh0 * (h0_hi + h0_lo) ----
    float h0n[2];
    {
      const f16* a0 = H0 + src*524288 + base_h;
      f32x4 acc0 = (f32x4){0,0,0,0}, acc1 = (f32x4){0,0,0,0};
#pragma unroll 4
      for (int c = 0; c < 32; ++c){
        f16x8 wf0 = *(const f16x8*)(lds + ((c*2+0) << 9) + (l << 3));
        f16x8 wf1 = *(const f16x8*)(lds + ((c*2+1) << 9) + (l << 3));
        f16x8 bh = *(const f16x8*)(a0 + c*16384);
        f16x8 bl = *(const f16x8*)(a0 + c*16384 + 8);
        acc0 = MFMA16(wf0, bh, acc0);
        acc0 = MFMA16(wf0, bl, acc0);
        acc1 = MFMA16(wf1, bh, acc1);
        acc1 = MFMA16(wf1, bl, acc1);
      }
      float xb = (s < 84) ? seq[(s << 8) + bcol] : yprev;
      f32x4 at[2] = {acc0, acc1};
#pragma unroll
      for (int t = 0; t < 2; ++t){
        float pi = at[t][0] + bias0t[t][0] + wi0t[t][0]*xb;
        float pf = at[t][1] + bias0t[t][1] + wi0t[t][1]*xb;
        float pg = at[t][2] + bias0t[t][2] + wi0t[t][2]*xb;
        float po = at[t][3] + bias0t[t][3] + wi0t[t][3]*xb;
        c0[t]  = sigf(pf)*c0[t] + sigf(pi)*thf(pg);
        h0n[t] = sigf(po)*thf(c0[t]);
        f16 hi = (f16)h0n[t];
        f16 lo = (f16)(h0n[t] - (float)hi);
        stage[(bcol << 4) + q + t*4]     = hi;
        stage[(bcol << 4) + 8 + q + t*4] = lo;
      }
    }
    __syncthreads();
    if (tid < 512){
      u32x4 v = ((const u32x4*)stage)[tid];
      st_dwordx4_sc((char*)(H0 + dst*524288 + (blk << 12)) + tid*16, v);
    }
    ++ep; gbar(flags, ep, tid, blk);

    // ---- phase B: gates1 = Wih1*h0new + Whh1*h1 ----
    float h1n[2];
    {
      const f16* b0 = H0 + dst*524288 + base_h;
      const f16* b1 = H1 + src*524288 + base_h;
      f32x4 acc0 = (f32x4){0,0,0,0}, acc1 = (f32x4){0,0,0,0};
#pragma unroll 4
      for (int c = 0; c < 32; ++c){
        f16x8 wa0 = *(const f16x8*)(lds + 32768 + ((c*2+0) << 9) + (l << 3));
        f16x8 wa1 = *(const f16x8*)(lds + 32768 + ((c*2+1) << 9) + (l << 3));
        f16x8 wb0 = *(const f16x8*)(whh1f + ((c*2+0) << 9) + (l << 3));
        f16x8 wb1 = *(const f16x8*)(whh1f + ((c*2+1) << 9) + (l << 3));
        f16x8 x0h = *(const f16x8*)(b0 + c*16384);
        f16x8 x0l = *(const f16x8*)(b0 + c*16384 + 8);
        f16x8 x1h = *(const f16x8*)(b1 + c*16384);
        f16x8 x1l = *(const f16x8*)(b1 + c*16384 + 8);
        acc0 = MFMA16(wa0, x0h, acc0);
        acc0 = MFMA16(wa0, x0l, acc0);
        acc0 = MFMA16(wb0, x1h, acc0);
        acc0 = MFMA16(wb0, x1l, acc0);
        acc1 = MFMA16(wa1, x0h, acc1);
        acc1 = MFMA16(wa1, x0l, acc1);
        acc1 = MFMA16(wb1, x1h, acc1);
        acc1 = MFMA16(wb1, x1l, acc1);
      }
      f32x4 at[2] = {acc0, acc1};
#pragma unroll
      for (int t = 0; t < 2; ++t){
        float pi = at[t][0] + bias1t[t][0];
        float pf = at[t][1] + bias1t[t][1];
        float pg = at[t][2] + bias1t[t][2];
        float po = at[t][3] + bias1t[t][3];
        c1[t]  = sigf(pf)*c1[t] + sigf(pi)*thf(pg);
        h1n[t] = sigf(po)*thf(c1[t]);
        f16 hi = (f16)h1n[t];
        f16 lo = (f16)(h1n[t] - (float)hi);
        stage[(bcol << 4) + q + t*4]     = hi;
        stage[(bcol << 4) + 8 + q + t*4] = lo;
      }
    }
    __syncthreads();
    if (tid < 512){
      u32x4 v = ((const u32x4*)stage)[tid];
      st_dwordx4_sc((char*)(H1 + dst*524288 + (blk << 12)) + tid*16, v);
    }

    // ---- fc partials with exact JAX dropout (tau = s-83) ----
    if (s >= 83){
      const int tau = s - 83;
      uint2 fk = tf2x32(0u, 42u, 0u, (unsigned)tau);
      unsigned n0 = ((unsigned)bcol << 10) + (unsigned)(j0 + q);
      unsigned n1 = n0 + 4u;
      float v = (drop_keep(fk, n0) ? h1n[0]*fcw0 : 0.f)
              + (drop_keep(fk, n1) ? h1n[1]*fcw1 : 0.f);
      v += __shfl_xor(v, 16, 64);
      v += __shfl_xor(v, 32, 64);
      if (q == 0) atomicAdd(y_acc + (tau << 8) + bcol, v);
      ++ep; gbar(flags, ep, tid, blk);
    }
  }

  // tail: y_23
  if (blk == 0 && q == 0) out[bcol*24 + 23] = fcb + y_acc[(23 << 8) + bcol];
}

extern "C" void kernel_launch(void* const* d_in, const int* in_sizes, int n_in,
                              void* d_out, int out_size, void* d_ws, size_t ws_size,
                              hipStream_t stream)
{
  const float* x    = (const float*)d_in[0];
  const float* cw   = (const float*)d_in[1];
  const float* cb   = (const float*)d_in[2];
  const float* Wih0 = (const float*)d_in[3];
  const float* Whh0 = (const float*)d_in[4];
  const float* bih0 = (const float*)d_in[5];
  const float* bhh0 = (const float*)d_in[6];
  const float* Wih1 = (const float*)d_in[7];
  const float* Whh1 = (const float*)d_in[8];
  const float* bih1 = (const float*)d_in[9];
  const float* bhh1 = (const float*)d_in[10];
  const float* fc_w = (const float*)d_in[11];
  const float* fc_b = (const float*)d_in[12];
  float* out = (float*)d_out;
  char*  ws  = (char*)d_ws;

  hipLaunchKernelGGL(k_init, dim3(1034), dim3(256), 0, stream,
                     (uint4*)(ws + H0_OFF), (uint4*)(ws + YACC_OFF), (uint4*)(ws + FLAG_OFF));
  hipLaunchKernelGGL(k_seq,  dim3(84), dim3(256), 0, stream, x, cw, cb, (float*)(ws + SEQ_OFF));
  hipLaunchKernelGGL(k_wpack, dim3(128), dim3(1024), 0, stream, Whh1, (f16*)(ws + WHH1_OFF));
  hipLaunchKernelGGL(k_main, dim3(128), dim3(1024), 139264, stream,
                     Wih0, Whh0, bih0, bhh0, Wih1, Whh1, bih1, bhh1,
                     fc_w, fc_b, ws, out);
}

// Round 7
// 4687.666 us; speedup vs baseline: 16.4438x; 1.5211x over previous
//
#include <hip/hip_runtime.h>
#include <stdint.h>

typedef _Float16 f16;
typedef f16  f16x8 __attribute__((ext_vector_type(8)));
typedef float f32x4 __attribute__((ext_vector_type(4)));
typedef unsigned u32x4 __attribute__((ext_vector_type(4)));

// ---------------- ws layout (byte offsets) ----------------
// H0/H1: 2 bufs x [k/8][b][hi8|lo8] f16 (1 MB per buf)
// WHH0F: fp16 MFMA A-frags of Whh0, [hgrp128][frag64][lane64][8] = 8 MB
// SEQ [84][256] f32 | YACC [24][256] f32 | FLAG 256 x 128B
#define H0_OFF    0u
#define H1_OFF    2097152u
#define WHH0F_OFF 4194304u
#define SEQ_OFF   12582912u
#define YACC_OFF  12668928u
#define FLAG_OFF  12693504u

__device__ __forceinline__ unsigned rotl32(unsigned x, int d){ return (x<<d)|(x>>(32-d)); }

// Threefry-2x32, 20 rounds, exactly JAX's key schedule. (bit-exact, proven R1-R6)
__device__ __forceinline__ uint2 tf2x32(unsigned k0, unsigned k1, unsigned x0, unsigned x1){
  unsigned kx = k0 ^ k1 ^ 0x1BD11BDAu;
  x0 += k0; x1 += k1;
#define TFR(r) { x0 += x1; x1 = rotl32(x1,(r)); x1 ^= x0; }
  TFR(13) TFR(15) TFR(26) TFR(6)  x0 += k1; x1 += kx + 1u;
  TFR(17) TFR(29) TFR(16) TFR(24) x0 += kx; x1 += k0 + 2u;
  TFR(13) TFR(15) TFR(26) TFR(6)  x0 += k0; x1 += k1 + 3u;
  TFR(17) TFR(29) TFR(16) TFR(24) x0 += k1; x1 += kx + 4u;
  TFR(13) TFR(15) TFR(26) TFR(6)  x0 += kx; x1 += k0 + 5u;
#undef TFR
  return make_uint2(x0, x1);
}

__device__ __forceinline__ bool drop_keep(uint2 fk, unsigned n){
  uint2 o = tf2x32(fk.x, fk.y, 0u, n);
  unsigned bits = o.x ^ o.y;
  float u = __uint_as_float((bits >> 9) | 0x3f800000u) - 1.0f;
  return u < 0.8f;
}

__device__ __forceinline__ float sigf(float x){ return 1.0f/(1.0f + __expf(-x)); }
__device__ __forceinline__ float thf(float x){ return 1.0f - 2.0f/(__expf(2.0f*x) + 1.0f); }

// ---- LLC-coherent (L2-bypassing) accessors (proven R4/R6) ----
__device__ __forceinline__ void st_dword_sc(void* p, unsigned v){
  asm volatile("global_store_dword %0, %1, off sc0 sc1" :: "v"(p), "v"(v) : "memory");
}
__device__ __forceinline__ void st_dwordx4_sc(void* p, u32x4 v){
  asm volatile("global_store_dwordx4 %0, %1, off sc0 sc1" :: "v"(p), "v"(v) : "memory");
}
__device__ __forceinline__ unsigned ld_dword_sc(const void* p){
  unsigned r;
  asm volatile("global_load_dword %0, %1, off sc0 sc1\n\ts_waitcnt vmcnt(0)"
               : "=v"(r) : "v"(p) : "memory");
  return r;
}

// grid barrier (proven R4/R6): vmcnt-drain + sc1 flag store; poll; one L2-inv on acquire.
__device__ __forceinline__ void gbar(unsigned* flags, unsigned e, int tid, int blk){
  asm volatile("s_waitcnt vmcnt(0)" ::: "memory");
  __syncthreads();
  if (tid == 0) st_dword_sc(flags + blk*32, e);
  if (tid < 256){
    unsigned* f = flags + tid*32;
    while (ld_dword_sc(f) < e) __builtin_amdgcn_s_sleep(1);
  }
  __syncthreads();
  __builtin_amdgcn_fence(__ATOMIC_ACQUIRE, "agent");
  __builtin_amdgcn_sched_barrier(0);
}

// ---- prep: zero h buffers + y_acc + flags ----
__global__ void k_init(uint4* __restrict__ hz, uint4* __restrict__ yz, uint4* __restrict__ fz){
  unsigned i = blockIdx.x*256u + threadIdx.x;
  if (i < 262144u){ hz[i] = uint4{0,0,0,0}; }
  else if (i < 263680u){ yz[i - 262144u] = uint4{0,0,0,0}; }
  else if (i < 265728u){ fz[i - 263680u] = uint4{0,0,0,0}; }
}

// ---- prep: conv1d(pad1,k3) + relu + maxpool2 -> seq[84][256] ----
__global__ void k_seq(const float* __restrict__ x, const float* __restrict__ cw,
                      const float* __restrict__ cb, float* __restrict__ seq){
  const int q = blockIdx.x;
  const int b = threadIdx.x;
  float best = -1e30f;
#pragma unroll
  for (int ssub = 0; ssub < 2; ++ssub){
    int p = 2*q + ssub;
    float acc = cb[0];
#pragma unroll
    for (int k = 0; k < 3; ++k){
      int t = p - 1 + k;
      if (t >= 0 && t < 168){
        const float* xp = x + ((size_t)b*192 + t)*8;
#pragma unroll
        for (int i = 0; i < 8; ++i) acc = fmaf(xp[i], cw[i*3 + k], acc);
      }
    }
    acc  = fmaxf(acc, 0.0f);
    best = fmaxf(best, acc);
  }
  seq[(q<<8) + b] = best;
}

// ---- prep: pack Whh0 (fp32 [4096][1024]) into fp16 MFMA A-frags per hgrp ----
__global__ void __launch_bounds__(512) k_wpack(const float* __restrict__ W, f16* __restrict__ dst){
  const int hgrp = blockIdx.x;       // 0..127
  const int tid = threadIdx.x;
  const int l   = tid & 63;
  const int w   = tid >> 6;          // 0..7
  const int j0  = hgrp << 3;
#pragma unroll
  for (int fi = 0; fi < 8; ++fi){
    const int f = (w << 3) + fi;     // 0..63
    const int c = f >> 1, T = f & 1;
    const int r = l & 15;
    const int u = (T << 2) + (r >> 2);
    const int g = r & 3;
    const float* src = W + (((size_t)((g << 10) + j0 + u)) << 10) + (c << 5) + ((l >> 4) << 3);
    float4 a = *(const float4*)src;
    float4 b = *(const float4*)(src + 4);
    f16x8 v;
    v[0]=(f16)a.x; v[1]=(f16)a.y; v[2]=(f16)a.z; v[3]=(f16)a.w;
    v[4]=(f16)b.x; v[5]=(f16)b.y; v[6]=(f16)b.z; v[7]=(f16)b.w;
    *(f16x8*)(dst + ((size_t)hgrp << 15) + (f << 9) + (l << 3)) = v;
  }
}

#define MFMA16(a,b,c) __builtin_amdgcn_mfma_f32_16x16x32_f16((a),(b),(c),0,0,0)

// ---- main persistent kernel: 256 blocks (128 hgrp x 2 bgrp) x 512 threads ----
__global__ void __launch_bounds__(512, 2) k_main(
    const float* __restrict__ Wih0, const float* __restrict__ Whh0,
    const float* __restrict__ bih0, const float* __restrict__ bhh0,
    const float* __restrict__ Wih1, const float* __restrict__ Whh1,
    const float* __restrict__ bih1, const float* __restrict__ bhh1,
    const float* __restrict__ fc_w, const float* __restrict__ fc_b,
    char* __restrict__ ws, float* __restrict__ out)
{
  extern __shared__ char smem_[];
  f16* lds = (f16*)smem_;          // halves: [0,32768) Wih1 frags | [32768,65536) Whh1 frags
  f16* stage = lds + 65536;        // [65536,67584): [128 local cols][hi8|lo8]

  const int tid  = threadIdx.x;
  const int blk  = blockIdx.x;
  const int hgrp = blk & 127;      // hidden units 8*hgrp..+7
  const int bgrp = blk >> 7;       // batch cols bgrp*128..+127
  const int j0   = hgrp << 3;
  const int l    = tid & 63;
  const int w8   = tid >> 6;       // wave 0..7, local cols w8*16..+16
  const int q    = l >> 4;
  const int c16  = l & 15;
  const int lcol = (w8 << 4) + c16;     // 0..127
  const int bcol = (bgrp << 7) + lcol;  // absolute batch col

  // ---- pack Wih1, Whh1 slices into LDS as MFMA A-frags (once) ----
  {
    const float* srcs[2] = {Wih1, Whh1};
#pragma unroll
    for (int m = 0; m < 2; ++m){
#pragma unroll
      for (int fi = 0; fi < 8; ++fi){
        const int f = (w8 << 3) + fi;
        const int c = f >> 1, T = f & 1;
        const int r = c16;
        const int uu = (T << 2) + (r >> 2);
        const int g = r & 3;
        const float* src = srcs[m] + (((size_t)((g << 10) + j0 + uu)) << 10) + (c << 5) + (q << 3);
        float4 a = *(const float4*)src;
        float4 b = *(const float4*)(src + 4);
        f16x8 v;
        v[0]=(f16)a.x; v[1]=(f16)a.y; v[2]=(f16)a.z; v[3]=(f16)a.w;
        v[4]=(f16)b.x; v[5]=(f16)b.y; v[6]=(f16)b.z; v[7]=(f16)b.w;
        *(f16x8*)(lds + m*32768 + (f << 9) + (l << 3)) = v;
      }
    }
  }
  __syncthreads();

  // ---- per-lane constants (units q and q+4) ----
  float bias0t[2][4], bias1t[2][4], wi0t[2][4];
#pragma unroll
  for (int t = 0; t < 2; ++t){
    const int uu = j0 + q + t*4;
#pragma unroll
    for (int g = 0; g < 4; ++g){
      int row = (g << 10) + uu;
      bias0t[t][g] = bih0[row] + bhh0[row];
      bias1t[t][g] = bih1[row] + bhh1[row];
      wi0t[t][g]   = Wih0[row];
    }
  }
  const float fcw0 = fc_w[j0 + q] * 1.25f;
  const float fcw1 = fc_w[j0 + q + 4] * 1.25f;
  const float fcb  = fc_b[0];

  const int base_h = (q << 12) + (bcol << 4);   // per-lane B-frag offset (halves)

  f16* H0 = (f16*)(ws + H0_OFF);   // per-buf 524288 halves
  f16* H1 = (f16*)(ws + H1_OFF);
  const f16* whh0f = (const f16*)(ws + WHH0F_OFF) + ((size_t)hgrp << 15);
  const float* seq = (const float*)(ws + SEQ_OFF);
  float* y_acc = (float*)(ws + YACC_OFF);
  unsigned* flags = (unsigned*)(ws + FLAG_OFF);

  float c0[2] = {0,0}, c1[2] = {0,0};
  float yprev = 0.f;
  unsigned ep = 0;

#pragma unroll 1
  for (int s = 0; s < 107; ++s){
    const int src = s & 1, dst = src ^ 1;

    if (s >= 84){
      const int tp = s - 84;
      yprev = fcb + y_acc[(tp << 8) + bcol];
      if (hgrp == 0 && q == 0) out[bcol*24 + tp] = yprev;
    }

    // ================= phase A: gates0 = Whh0*(h0_hi+h0_lo) =================
    float h0n[2];
    {
      const f16* a0  = H0 + src*524288 + base_h;
      const f16* wfp = whh0f + (l << 3);
      f16x8 Wb0[2][4], Wb1[2][4], Bh[2][4], Bl[2][4];
      f32x4 acc0 = (f32x4){0,0,0,0}, acc1 = (f32x4){0,0,0,0};
#define LDA(B, CB) { _Pragma("unroll") for (int i = 0; i < 4; ++i){ const int c = (CB)+i; \
      Wb0[B][i] = *(const f16x8*)(wfp + ((2*c  ) << 9)); \
      Wb1[B][i] = *(const f16x8*)(wfp + ((2*c+1) << 9)); \
      Bh [B][i] = *(const f16x8*)(a0 + c*16384); \
      Bl [B][i] = *(const f16x8*)(a0 + c*16384 + 8); } }
#define MMA_A(B) { _Pragma("unroll") for (int i = 0; i < 4; ++i){ \
      acc0 = MFMA16(Wb0[B][i], Bh[B][i], acc0); acc0 = MFMA16(Wb0[B][i], Bl[B][i], acc0); \
      acc1 = MFMA16(Wb1[B][i], Bh[B][i], acc1); acc1 = MFMA16(Wb1[B][i], Bl[B][i], acc1); } }
      LDA(0, 0)
#pragma unroll
      for (int cb = 0; cb < 8; ++cb){
        if ((cb & 1) == 0){ if (cb < 7) LDA(1, (cb+1)*4) MMA_A(0) }
        else              { if (cb < 7) LDA(0, (cb+1)*4) MMA_A(1) }
      }
#undef LDA
#undef MMA_A
      float xb = (s < 84) ? seq[(s << 8) + bcol] : yprev;
      f32x4 at[2] = {acc0, acc1};
#pragma unroll
      for (int t = 0; t < 2; ++t){
        float pi = at[t][0] + bias0t[t][0] + wi0t[t][0]*xb;
        float pf = at[t][1] + bias0t[t][1] + wi0t[t][1]*xb;
        float pg = at[t][2] + bias0t[t][2] + wi0t[t][2]*xb;
        float po = at[t][3] + bias0t[t][3] + wi0t[t][3]*xb;
        c0[t]  = sigf(pf)*c0[t] + sigf(pi)*thf(pg);
        h0n[t] = sigf(po)*thf(c0[t]);
        f16 hi = (f16)h0n[t];
        f16 lo = (f16)(h0n[t] - (float)hi);
        stage[(lcol << 4) + q + t*4]     = hi;
        stage[(lcol << 4) + 8 + q + t*4] = lo;
      }
    }
    __syncthreads();
    if (tid < 256){
      u32x4 v = ((const u32x4*)stage)[tid];
      st_dwordx4_sc((char*)(H0 + dst*524288 + (hgrp << 12) + (bgrp << 11)) + tid*16, v);
    }
    ++ep; gbar(flags, ep, tid, blk);

    // ================= phase B: gates1 = Wih1*h0new + Whh1*h1 =================
    float h1n[2];
    {
      const f16* b0 = H0 + dst*524288 + base_h;
      const f16* b1 = H1 + src*524288 + base_h;
      f16x8 X0h[2][4], X0l[2][4], X1h[2][4], X1l[2][4];
      f32x4 acc0 = (f32x4){0,0,0,0}, acc1 = (f32x4){0,0,0,0};
#define LDB(B, CB) { _Pragma("unroll") for (int i = 0; i < 4; ++i){ const int c = (CB)+i; \
      X0h[B][i] = *(const f16x8*)(b0 + c*16384); \
      X0l[B][i] = *(const f16x8*)(b0 + c*16384 + 8); \
      X1h[B][i] = *(const f16x8*)(b1 + c*16384); \
      X1l[B][i] = *(const f16x8*)(b1 + c*16384 + 8); } }
#define MMA_B(B, CB) { _Pragma("unroll") for (int i = 0; i < 4; ++i){ const int c = (CB)+i; \
      f16x8 wa0 = *(const f16x8*)(lds + ((2*c  ) << 9) + (l << 3)); \
      f16x8 wa1 = *(const f16x8*)(lds + ((2*c+1) << 9) + (l << 3)); \
      f16x8 wb0 = *(const f16x8*)(lds + 32768 + ((2*c  ) << 9) + (l << 3)); \
      f16x8 wb1 = *(const f16x8*)(lds + 32768 + ((2*c+1) << 9) + (l << 3)); \
      acc0 = MFMA16(wa0, X0h[B][i], acc0); acc0 = MFMA16(wa0, X0l[B][i], acc0); \
      acc0 = MFMA16(wb0, X1h[B][i], acc0); acc0 = MFMA16(wb0, X1l[B][i], acc0); \
      acc1 = MFMA16(wa1, X0h[B][i], acc1); acc1 = MFMA16(wa1, X0l[B][i], acc1); \
      acc1 = MFMA16(wb1, X1h[B][i], acc1); acc1 = MFMA16(wb1, X1l[B][i], acc1); } }
      LDB(0, 0)
#pragma unroll
      for (int cb = 0; cb < 8; ++cb){
        if ((cb & 1) == 0){ if (cb < 7) LDB(1, (cb+1)*4) MMA_B(0, cb*4) }
        else              { if (cb < 7) LDB(0, (cb+1)*4) MMA_B(1, cb*4) }
      }
#undef LDB
#undef MMA_B
      f32x4 at[2] = {acc0, acc1};
#pragma unroll
      for (int t = 0; t < 2; ++t){
        float pi = at[t][0] + bias1t[t][0];
        float pf = at[t][1] + bias1t[t][1];
        float pg = at[t][2] + bias1t[t][2];
        float po = at[t][3] + bias1t[t][3];
        c1[t]  = sigf(pf)*c1[t] + sigf(pi)*thf(pg);
        h1n[t] = sigf(po)*thf(c1[t]);
        f16 hi = (f16)h1n[t];
        f16 lo = (f16)(h1n[t] - (float)hi);
        stage[(lcol << 4) + q + t*4]     = hi;
        stage[(lcol << 4) + 8 + q + t*4] = lo;
      }
    }
    __syncthreads();
    if (tid < 256){
      u32x4 v = ((const u32x4*)stage)[tid];
      st_dwordx4_sc((char*)(H1 + dst*524288 + (hgrp << 12) + (bgrp << 11)) + tid*16, v);
    }
    __syncthreads();   // protect stage from next phase-A overwrite (latent race in R6)

    // ---- fc partials with exact JAX dropout (tau = s-83) ----
    if (s >= 83){
      const int tau = s - 83;
      uint2 fk = tf2x32(0u, 42u, 0u, (unsigned)tau);
      unsigned n0 = ((unsigned)bcol << 10) + (unsigned)(j0 + q);
      unsigned n1 = n0 + 4u;
      float v = (drop_keep(fk, n0) ? h1n[0]*fcw0 : 0.f)
              + (drop_keep(fk, n1) ? h1n[1]*fcw1 : 0.f);
      v += __shfl_xor(v, 16, 64);
      v += __shfl_xor(v, 32, 64);
      if (q == 0) atomicAdd(y_acc + (tau << 8) + bcol, v);
      ++ep; gbar(flags, ep, tid, blk);
    }
  }

  // tail: y_23
  if (hgrp == 0 && q == 0) out[bcol*24 + 23] = fcb + y_acc[(23 << 8) + bcol];
}

extern "C" void kernel_launch(void* const* d_in, const int* in_sizes, int n_in,
                              void* d_out, int out_size, void* d_ws, size_t ws_size,
                              hipStream_t stream)
{
  const float* x    = (const float*)d_in[0];
  const float* cw   = (const float*)d_in[1];
  const float* cb   = (const float*)d_in[2];
  const float* Wih0 = (const float*)d_in[3];
  const float* Whh0 = (const float*)d_in[4];
  const float* bih0 = (const float*)d_in[5];
  const float* bhh0 = (const float*)d_in[6];
  const float* Wih1 = (const float*)d_in[7];
  const float* Whh1 = (const float*)d_in[8];
  const float* bih1 = (const float*)d_in[9];
  const float* bhh1 = (const float*)d_in[10];
  const float* fc_w = (const float*)d_in[11];
  const float* fc_b = (const float*)d_in[12];
  float* out = (float*)d_out;
  char*  ws  = (char*)d_ws;

  hipLaunchKernelGGL(k_init, dim3(1038), dim3(256), 0, stream,
                     (uint4*)(ws + H0_OFF), (uint4*)(ws + YACC_OFF), (uint4*)(ws + FLAG_OFF));
  hipLaunchKernelGGL(k_seq,  dim3(84), dim3(256), 0, stream, x, cw, cb, (float*)(ws + SEQ_OFF));
  hipLaunchKernelGGL(k_wpack, dim3(128), dim3(512), 0, stream, Whh0, (f16*)(ws + WHH0F_OFF));
  hipLaunchKernelGGL(k_main, dim3(256), dim3(512), 135168, stream,
                     Wih0, Whh0, bih0, bhh0, Wih1, Whh1, bih1, bhh1,
                     fc_w, fc_b, ws, out);
}